// Round 12
// baseline (224.555 us; speedup 1.0000x reference)
//
#include <hip/hip_runtime.h>
#include <hip/hip_bf16.h>

typedef __attribute__((ext_vector_type(8))) short short8;
typedef __attribute__((ext_vector_type(4))) float floatx4;
typedef __attribute__((ext_vector_type(2))) float float2v;
typedef __attribute__((ext_vector_type(4))) int int4v;
typedef __attribute__((ext_vector_type(2))) int int2v;

__device__ __forceinline__ float b2f(short s) {
    unsigned u = ((unsigned)(unsigned short)s) << 16;
    float f; __builtin_memcpy(&f, &u, 4); return f;
}
__device__ __forceinline__ short f2b(float f) {
    __hip_bfloat16 hb = __float2bfloat16(f);   // RNE
    unsigned short us; __builtin_memcpy(&us, &hb, 2);
    return (short)us;
}
__device__ __forceinline__ float2v bpair(int p) {
    unsigned ulo = ((unsigned)p) << 16;
    unsigned uhi = ((unsigned)p) & 0xFFFF0000u;
    float flo, fhi;
    __builtin_memcpy(&flo, &ulo, 4);
    __builtin_memcpy(&fhi, &uhi, 4);
    float2v r; r.x = flo; r.y = fhi; return r;
}

// ---- prep: conversions + weight transposes + padded-CSR build (hist+scatter) ----
// Padded CSR: srcs[d*64 + pos], pos from one atomicAdd. Random graph: mean deg 17,
// P(deg>63) < 1e-20 per node — cap 64 is safe; store guarded anyway.
__global__ void prep_all(const float* __restrict__ x,
                         const float* __restrict__ W1l, const float* __restrict__ W1r,
                         const float* __restrict__ W2l, const float* __restrict__ W2r,
                         short* __restrict__ xb, short* __restrict__ w1t,
                         short* __restrict__ w2t, int nx,
                         const int* __restrict__ esrc, const int* __restrict__ edst,
                         int E, int N, int* __restrict__ counts, int* __restrict__ srcs) {
    int tid = blockIdx.x * blockDim.x + threadIdx.x;
    int ET = E + N;
    if (tid < ET) {
        int d, s;
        if (tid < E) { d = edst[tid]; s = esrc[tid]; }
        else { d = tid - E; s = d; }
        int pos = atomicAdd(&counts[d], 1);
        if (pos < 64) srcs[(d << 6) + pos] = s;
    }
    int idx = tid;
    if (idx < nx) { xb[idx] = f2b(x[idx]); return; }
    idx -= nx;
    if (idx < 131072) {
        int n = idx >> 7, k = idx & 127;
        float v = (n < 512) ? W1l[k * 512 + n] : W1r[k * 512 + (n - 512)];
        w1t[idx] = f2b(v);
        return;
    }
    idx -= 131072;
    if (idx < 65536) {
        int n = idx >> 9, k = idx & 511;
        float v = (n < 64) ? W2l[k * 64 + n] : W2r[k * 64 + (n - 64)];
        w2t[idx] = f2b(v);
    }
}

// ---------------- GEMM1: A[M,128] @ w1t[1024,128]^T -> xl1|xr1 [M,512] each -------
// 64M x 128N tile, K=128 staged once; LDS-repacked coalesced epilogue.
__global__ __launch_bounds__(256) void gemm1(const short* __restrict__ A,
                                             const short* __restrict__ Bt,
                                             short* __restrict__ xl1, short* __restrict__ xr1,
                                             int M) {
    __shared__ short As[64 * 136];    // also reused as 64x136 C-staging
    __shared__ short Bs[128 * 136];
    int t = threadIdx.x;
    int w = t >> 6, L = t & 63, q = L >> 4, s = L & 15;
    int M0 = blockIdx.y * 64, N0 = blockIdx.x * 128;
    #pragma unroll
    for (int i = 0; i < 4; ++i) {       // A: 64 rows x 16 chunks of 8
        int c = t + i * 256;
        int r = c >> 4, col = (c & 15) * 8;
        int gr = M0 + r;
        short8 v = {};
        if (gr < M) v = *(const short8*)(A + (size_t)gr * 128 + col);
        *(short8*)(&As[r * 136 + col]) = v;
    }
    #pragma unroll
    for (int i = 0; i < 8; ++i) {       // B: 128 rows x 16 chunks
        int c = t + i * 256;
        int r = c >> 4, col = (c & 15) * 8;
        short8 v = *(const short8*)(Bt + (size_t)(N0 + r) * 128 + col);
        *(short8*)(&Bs[r * 136 + col]) = v;
    }
    __syncthreads();
    short8 a[4];
    #pragma unroll
    for (int kk = 0; kk < 4; ++kk)
        a[kk] = *(const short8*)(&As[(w * 16 + s) * 136 + kk * 32 + q * 8]);
    floatx4 acc[8] = {};
    #pragma unroll
    for (int tt = 0; tt < 8; ++tt) {
        #pragma unroll
        for (int kk = 0; kk < 4; ++kk) {
            short8 b = *(const short8*)(&Bs[(tt * 16 + s) * 136 + kk * 32 + q * 8]);
            acc[tt] = __builtin_amdgcn_mfma_f32_16x16x32_bf16(a[kk], b, acc[tt], 0, 0, 0);
        }
    }
    __syncthreads();                    // all As/Bs reads done; reuse As as C stage
    #pragma unroll
    for (int tt = 0; tt < 8; ++tt) {
        #pragma unroll
        for (int rg = 0; rg < 4; ++rg) {
            int rl = w * 16 + q * 4 + rg;     // C/D: row=quad*4+reg, col=lane&15
            As[rl * 136 + tt * 16 + s] = f2b(acc[tt][rg]);
        }
    }
    __syncthreads();
    short* Cb = (N0 < 512) ? xl1 : xr1;
    int cb = (N0 < 512) ? N0 : N0 - 512;
    #pragma unroll
    for (int i = 0; i < 4; ++i) {       // 64 rows x 16 chunks of 8
        int c = t + i * 256;
        int r = c >> 4, col = (c & 15) * 8;
        int row = M0 + r;
        if (row < M) {
            short8 v = *(const short8*)(&As[r * 136 + col]);
            *(short8*)(Cb + (size_t)row * 512 + cb + col) = v;
        }
    }
}

// ------- FUSED: Layer-1 GATv2 (wave/node -> LDS h1) + GEMM2 (LDS A) -> x2 ---------
// 1024 threads = 16 waves = 16 nodes/block. N must be divisible by 16 (20000 ok).
__global__ __launch_bounds__(1024) void gat1_gemm2(
                       const short* __restrict__ xl, const short* __restrict__ xr,
                       const int* __restrict__ counts, const int* __restrict__ srcs,
                       const float* __restrict__ att, const float* __restrict__ bias,
                       const short* __restrict__ w2t, short* __restrict__ x2, int Nn) {
    __shared__ short h1s[16 * 520];   // 16 h1 rows, +8 pad
    __shared__ short Bs[128 * 136];   // K-chunk of w2t; reused as f32 C-combine
    int t = threadIdx.x;
    int w = t >> 6, L = t & 63;
    int i = blockIdx.x * 16 + w;
    // ---------------- phase 1: GATv2 per wave ----------------
    {
        int c0 = L * 8;
        float2v xrv[4], at[4];
        {
            int4v x4 = *(const int4v*)(xr + (size_t)i * 512 + c0);
            #pragma unroll
            for (int c = 0; c < 4; ++c) {
                xrv[c] = bpair(x4[c]);
                at[c].x = att[c0 + 2 * c];
                at[c].y = att[c0 + 2 * c + 1];
            }
        }
        float2v acc[4] = {};
        float dnm = 0.f;
        int k = i << 6;
        int deg = counts[i]; deg = deg > 64 ? 64 : deg;
        int ke = k + deg;
        for (; k + 1 < ke; k += 2) {
            int j0 = srcs[k], j1 = srcs[k + 1];
            int4v a4 = *(const int4v*)(xl + (size_t)j0 * 512 + c0);
            int4v b4 = *(const int4v*)(xl + (size_t)j1 * 512 + c0);
            float2v v0[4], v1[4];
            float2v p0 = {}, p1 = {};
            #pragma unroll
            for (int c = 0; c < 4; ++c) {
                v0[c] = bpair(a4[c]);
                float2v tv = v0[c] + xrv[c];
                p0 += at[c] * __builtin_elementwise_max(tv, 0.2f * tv);   // leaky 0.2
                v1[c] = bpair(b4[c]);
                float2v tw = v1[c] + xrv[c];
                p1 += at[c] * __builtin_elementwise_max(tw, 0.2f * tw);
            }
            float s0 = p0.x + p0.y, s1 = p1.x + p1.y;
            s0 += __shfl_xor(s0, 1, 64); s0 += __shfl_xor(s0, 2, 64); s0 += __shfl_xor(s0, 4, 64);
            s1 += __shfl_xor(s1, 1, 64); s1 += __shfl_xor(s1, 2, 64); s1 += __shfl_xor(s1, 4, 64);
            float e0 = __expf(s0), e1 = __expf(s1);
            dnm += e0 + e1;
            float2v e02; e02.x = e0; e02.y = e0;
            float2v e12; e12.x = e1; e12.y = e1;
            #pragma unroll
            for (int c = 0; c < 4; ++c) {
                acc[c] += e02 * v0[c];
                acc[c] += e12 * v1[c];
            }
        }
        if (k < ke) {
            int j = srcs[k];
            int4v a4 = *(const int4v*)(xl + (size_t)j * 512 + c0);
            float2v v0[4], p0 = {};
            #pragma unroll
            for (int c = 0; c < 4; ++c) {
                v0[c] = bpair(a4[c]);
                float2v tv = v0[c] + xrv[c];
                p0 += at[c] * __builtin_elementwise_max(tv, 0.2f * tv);
            }
            float s0 = p0.x + p0.y;
            s0 += __shfl_xor(s0, 1, 64); s0 += __shfl_xor(s0, 2, 64); s0 += __shfl_xor(s0, 4, 64);
            float e0 = __expf(s0);
            dnm += e0;
            float2v e02; e02.x = e0; e02.y = e0;
            #pragma unroll
            for (int c = 0; c < 4; ++c) acc[c] += e02 * v0[c];
        }
        float inv = 1.f / dnm;
        short8 o8;
        #pragma unroll
        for (int c = 0; c < 4; ++c) {
            float ox = fmaf(acc[c].x, inv, bias[c0 + 2 * c]);
            float oy = fmaf(acc[c].y, inv, bias[c0 + 2 * c + 1]);
            ox = ox > 0.f ? ox : __expf(ox) - 1.f;          // ELU
            oy = oy > 0.f ? oy : __expf(oy) - 1.f;
            o8[2 * c] = f2b(ox);
            o8[2 * c + 1] = f2b(oy);
        }
        *(short8*)(&h1s[w * 520 + c0]) = o8;
    }
    __syncthreads();
    // ---------------- phase 2: x2[16,128] = h1s[16,512] @ w2t[128,512]^T ----------
    int q = L >> 4, s = L & 15;
    int tt = w & 7, kh = w >> 3;          // col-tile 0..7, K-half 0..1
    floatx4 cacc = {};
    for (int k0 = 0; k0 < 512; k0 += 128) {
        #pragma unroll
        for (int i2 = 0; i2 < 2; ++i2) {  // stage Bs: 128 rows x 16 chunks of 8
            int c = t + i2 * 1024;
            int r = c >> 4, col = (c & 15) * 8;
            short8 v = *(const short8*)(w2t + (size_t)r * 512 + k0 + col);
            *(short8*)(&Bs[r * 136 + col]) = v;
        }
        __syncthreads();
        #pragma unroll
        for (int kk = 0; kk < 2; ++kk) {
            short8 a = *(const short8*)(&h1s[s * 520 + k0 + kh * 64 + kk * 32 + q * 8]);
            short8 b = *(const short8*)(&Bs[(tt * 16 + s) * 136 + kh * 64 + kk * 32 + q * 8]);
            cacc = __builtin_amdgcn_mfma_f32_16x16x32_bf16(a, b, cacc, 0, 0, 0);
        }
        __syncthreads();
    }
    float* Cp = (float*)Bs;               // 8 tiles x 256 floats = 8 KB
    if (kh == 1) {
        #pragma unroll
        for (int rg = 0; rg < 4; ++rg)
            Cp[tt * 256 + (q * 4 + rg) * 16 + s] = cacc[rg];
    }
    __syncthreads();
    if (kh == 0) {
        #pragma unroll
        for (int rg = 0; rg < 4; ++rg) {
            float v = cacc[rg] + Cp[tt * 256 + (q * 4 + rg) * 16 + s];
            int row = blockIdx.x * 16 + q * 4 + rg;
            x2[(size_t)row * 128 + tt * 16 + s] = f2b(v);
        }
    }
}

// ---------------- Layer-2 GATv2 + final linear: 16-lane x 4-ch, 4 edges/iter ------
__global__ __launch_bounds__(256) void gat_l2_fin(const short* __restrict__ x2,
                        const int* __restrict__ counts, const int* __restrict__ srcs,
                        const float* __restrict__ att, const float* __restrict__ bias,
                        const float* __restrict__ Wlin, const float* __restrict__ blin,
                        float* __restrict__ out, int Nn) {
    __shared__ float Ws[2048];
    __shared__ float bs[32];
    __shared__ float h2s[4][64];
    int t = threadIdx.x;
    for (int idx = t; idx < 2048; idx += 256) Ws[idx] = Wlin[idx];
    if (t < 32) bs[t] = blin[t];
    __syncthreads();
    int w = t >> 6, L = t & 63;
    int i = blockIdx.x * 4 + w;
    if (i >= Nn) return;
    int g = L >> 4;
    int c4 = (L & 15) * 4;
    float2v xrv[2], at[2];
    {
        int2v xv = *(const int2v*)(x2 + (size_t)i * 128 + 64 + c4);
        xrv[0] = bpair(xv.x);
        xrv[1] = bpair(xv.y);
        floatx4 a4 = *(const floatx4*)(att + c4);
        at[0].x = a4[0]; at[0].y = a4[1];
        at[1].x = a4[2]; at[1].y = a4[3];
    }
    float dnm = 0.f;
    float2v acc0 = {}, acc1 = {};
    int kb = i << 6;
    int deg = counts[i]; deg = deg > 64 ? 64 : deg;
    int ke = kb + deg;
    for (int k0 = kb; k0 < ke; k0 += 4) {
        int k = k0 + g;
        bool val = k < ke;
        int j = srcs[val ? k : kb];         // slot kb always populated (deg >= 1)
        int2v vv = *(const int2v*)(x2 + (size_t)j * 128 + c4);
        float2v v0 = bpair(vv.x), v1 = bpair(vv.y);
        float2v t0 = v0 + xrv[0], t1 = v1 + xrv[1];
        float2v pp = at[0] * __builtin_elementwise_max(t0, 0.2f * t0)
                   + at[1] * __builtin_elementwise_max(t1, 0.2f * t1);
        float p = pp.x + pp.y;
        p += __shfl_xor(p, 1, 64); p += __shfl_xor(p, 2, 64);
        p += __shfl_xor(p, 4, 64); p += __shfl_xor(p, 8, 64);   // 16-lane reduce
        float e = val ? __expf(p) : 0.f;
        dnm += e;
        float2v e2; e2.x = e; e2.y = e;
        acc0 += e2 * v0;
        acc1 += e2 * v1;
    }
    #pragma unroll
    for (int m = 16; m <= 32; m <<= 1) {
        dnm += __shfl_xor(dnm, m, 64);
        acc0.x += __shfl_xor(acc0.x, m, 64);
        acc0.y += __shfl_xor(acc0.y, m, 64);
        acc1.x += __shfl_xor(acc1.x, m, 64);
        acc1.y += __shfl_xor(acc1.y, m, 64);
    }
    float inv = 1.f / dnm;
    floatx4 bv = *(const floatx4*)(bias + c4);
    float o0 = fmaf(acc0.x, inv, bv[0]);
    float o1 = fmaf(acc0.y, inv, bv[1]);
    float o2 = fmaf(acc1.x, inv, bv[2]);
    float o3 = fmaf(acc1.y, inv, bv[3]);
    o0 = o0 > 0.f ? o0 : __expf(o0) - 1.f;   // ELU (h2)
    o1 = o1 > 0.f ? o1 : __expf(o1) - 1.f;
    o2 = o2 > 0.f ? o2 : __expf(o2) - 1.f;
    o3 = o3 > 0.f ? o3 : __expf(o3) - 1.f;
    if (L < 16) {
        floatx4 hv; hv[0] = o0; hv[1] = o1; hv[2] = o2; hv[3] = o3;
        *(floatx4*)(&h2s[w][c4]) = hv;       // wave-internal: no barrier needed
    }
    int oc = L & 31;
    float accl = 0.f;
    #pragma unroll
    for (int kk = 0; kk < 16; ++kk) {
        floatx4 h = *(const floatx4*)(&h2s[w][kk * 4]);
        accl = fmaf(h[0], Ws[(kk * 4 + 0) * 32 + oc], accl);
        accl = fmaf(h[1], Ws[(kk * 4 + 1) * 32 + oc], accl);
        accl = fmaf(h[2], Ws[(kk * 4 + 2) * 32 + oc], accl);
        accl = fmaf(h[3], Ws[(kk * 4 + 3) * 32 + oc], accl);
    }
    if (L < 32) {
        float r = accl + bs[oc];
        r = r > 0.f ? r : __expf(r) - 1.f;
        out[(size_t)i * 32 + oc] = r;
    }
}

extern "C" void kernel_launch(void* const* d_in, const int* in_sizes, int n_in,
                              void* d_out, int out_size, void* d_ws, size_t ws_size,
                              hipStream_t stream) {
    const float* x    = (const float*)d_in[0];
    const int*   ei   = (const int*)d_in[1];
    const float* W1l  = (const float*)d_in[2];
    const float* W1r  = (const float*)d_in[3];
    const float* att1 = (const float*)d_in[4];
    const float* b1   = (const float*)d_in[5];
    const float* W2l  = (const float*)d_in[6];
    const float* W2r  = (const float*)d_in[7];
    const float* att2 = (const float*)d_in[8];
    const float* b2   = (const float*)d_in[9];
    const float* Wlin = (const float*)d_in[10];
    const float* blin = (const float*)d_in[11];

    const int N  = in_sizes[0] / 128;   // 20000 (divisible by 16)
    const int E  = in_sizes[1] / 2;     // 320000

    char* w = (char*)d_ws;
    size_t cur = 0;
    auto take = [&](size_t bytes) -> void* {
        void* p = w + cur;
        cur = (cur + bytes + 255) & ~(size_t)255;
        return p;
    };
    int*   counts = (int*)take((size_t)N * 4);
    int*   srcs   = (int*)take((size_t)N * 64 * 4);       // padded CSR, stride 64
    short* xb     = (short*)take((size_t)N * 128 * 2);
    short* w1t    = (short*)take((size_t)1024 * 128 * 2);
    short* w2t    = (short*)take((size_t)128 * 512 * 2);
    short* xl1    = (short*)take((size_t)N * 512 * 2);
    short* xr1    = (short*)take((size_t)N * 512 * 2);
    short* x2     = (short*)take((size_t)N * 128 * 2);    // xl2 | xr2

    hipMemsetAsync(counts, 0, (size_t)N * 4, stream);
    int nprep = N * 128 + 131072 + 65536;
    prep_all<<<(nprep + 255) / 256, 256, 0, stream>>>(x, W1l, W1r, W2l, W2r, xb, w1t, w2t,
                                                      N * 128, ei, ei + E, E, N, counts, srcs);

    gemm1<<<dim3(8, (N + 63) / 64), 256, 0, stream>>>(xb, w1t, xl1, xr1, N);
    gat1_gemm2<<<N / 16, 1024, 0, stream>>>(xl1, xr1, counts, srcs, att1, b1, w2t, x2, N);
    gat_l2_fin<<<(N + 3) / 4, 256, 0, stream>>>(x2, counts, srcs, att2, b2, Wlin, blin,
                                                (float*)d_out, N);
}

// Round 14
// 216.495 us; speedup vs baseline: 1.0372x; 1.0372x over previous
//
#include <hip/hip_runtime.h>
#include <hip/hip_bf16.h>

typedef __attribute__((ext_vector_type(8))) short short8;
typedef __attribute__((ext_vector_type(4))) short shortx4;
typedef __attribute__((ext_vector_type(4))) float floatx4;
typedef __attribute__((ext_vector_type(2))) float float2v;
typedef __attribute__((ext_vector_type(4))) int int4v;

__device__ __forceinline__ float b2f(short s) {
    unsigned u = ((unsigned)(unsigned short)s) << 16;
    float f; __builtin_memcpy(&f, &u, 4); return f;
}
__device__ __forceinline__ short f2b(float f) {
    __hip_bfloat16 hb = __float2bfloat16(f);   // RNE
    unsigned short us; __builtin_memcpy(&us, &hb, 2);
    return (short)us;
}
__device__ __forceinline__ float2v bpair(int p) {
    unsigned ulo = ((unsigned)p) << 16;
    unsigned uhi = ((unsigned)p) & 0xFFFF0000u;
    float flo, fhi;
    __builtin_memcpy(&flo, &ulo, 4);
    __builtin_memcpy(&fhi, &uhi, 4);
    float2v r; r.x = flo; r.y = fhi; return r;
}

// ---- prep: weight transposes + padded-CSR build (hist+scatter fused) ------------
// Padded CSR: srcs[d*64 + pos], pos from one atomicAdd. Random graph: mean deg 17,
// P(deg>63) < 1e-20 per node — cap 64 safe; store guarded anyway.
__global__ void prep_all(const float* __restrict__ W1l, const float* __restrict__ W1r,
                         const float* __restrict__ W2l, const float* __restrict__ W2r,
                         short* __restrict__ w1t, short* __restrict__ w2t,
                         const int* __restrict__ esrc, const int* __restrict__ edst,
                         int E, int N, int* __restrict__ counts, int* __restrict__ srcs) {
    int tid = blockIdx.x * blockDim.x + threadIdx.x;
    int ET = E + N;
    if (tid < ET) {
        int d, s;
        if (tid < E) { d = edst[tid]; s = esrc[tid]; }
        else { d = tid - E; s = d; }
        int pos = atomicAdd(&counts[d], 1);
        if (pos < 64) srcs[(d << 6) + pos] = s;
    }
    int idx = tid;
    if (idx < 131072) {
        int n = idx >> 7, k = idx & 127;
        float v = (n < 512) ? W1l[k * 512 + n] : W1r[k * 512 + (n - 512)];
        w1t[idx] = f2b(v);
        return;
    }
    idx -= 131072;
    if (idx < 65536) {
        int n = idx >> 9, k = idx & 511;
        float v = (n < 64) ? W2l[k * 64 + n] : W2r[k * 64 + (n - 64)];
        w2t[idx] = f2b(v);
    }
}

// ---------------- GEMM1: x[M,128](f32) @ w1t[1024,128]^T -> xl1|xr1 [M,512] -------
// 64M x 128N tile, K=128 staged once; A converted f32->bf16 during staging;
// LDS-repacked coalesced epilogue.
__global__ __launch_bounds__(256) void gemm1(const float* __restrict__ X,
                                             const short* __restrict__ Bt,
                                             short* __restrict__ xl1, short* __restrict__ xr1,
                                             int M) {
    __shared__ short As[64 * 136];    // also reused as 64x136 C-staging
    __shared__ short Bs[128 * 136];
    int t = threadIdx.x;
    int w = t >> 6, L = t & 63, q = L >> 4, s = L & 15;
    int M0 = blockIdx.y * 64, N0 = blockIdx.x * 128;
    #pragma unroll
    for (int i = 0; i < 8; ++i) {       // A: 64 rows x 32 float4-chunks, cvt->bf16
        int c = t + i * 256;
        int r = c >> 5, col = (c & 31) * 4;
        int gr = M0 + r;
        floatx4 v = {};
        if (gr < M) v = *(const floatx4*)(X + (size_t)gr * 128 + col);
        shortx4 s4;
        #pragma unroll
        for (int j = 0; j < 4; ++j) s4[j] = f2b(v[j]);
        *(shortx4*)(&As[r * 136 + col]) = s4;
    }
    #pragma unroll
    for (int i = 0; i < 8; ++i) {       // B: 128 rows x 16 chunks of 8 (bf16)
        int c = t + i * 256;
        int r = c >> 4, col = (c & 15) * 8;
        short8 v = *(const short8*)(Bt + (size_t)(N0 + r) * 128 + col);
        *(short8*)(&Bs[r * 136 + col]) = v;
    }
    __syncthreads();
    short8 a[4];
    #pragma unroll
    for (int kk = 0; kk < 4; ++kk)
        a[kk] = *(const short8*)(&As[(w * 16 + s) * 136 + kk * 32 + q * 8]);
    floatx4 acc[8] = {};
    #pragma unroll
    for (int tt = 0; tt < 8; ++tt) {
        #pragma unroll
        for (int kk = 0; kk < 4; ++kk) {
            short8 b = *(const short8*)(&Bs[(tt * 16 + s) * 136 + kk * 32 + q * 8]);
            acc[tt] = __builtin_amdgcn_mfma_f32_16x16x32_bf16(a[kk], b, acc[tt], 0, 0, 0);
        }
    }
    __syncthreads();                    // all As/Bs reads done; reuse As as C stage
    #pragma unroll
    for (int tt = 0; tt < 8; ++tt) {
        #pragma unroll
        for (int rg = 0; rg < 4; ++rg) {
            int rl = w * 16 + q * 4 + rg;     // C/D: row=quad*4+reg, col=lane&15
            As[rl * 136 + tt * 16 + s] = f2b(acc[tt][rg]);
        }
    }
    __syncthreads();
    short* Cb = (N0 < 512) ? xl1 : xr1;
    int cb = (N0 < 512) ? N0 : N0 - 512;
    #pragma unroll
    for (int i = 0; i < 4; ++i) {       // 64 rows x 16 chunks of 8
        int c = t + i * 256;
        int r = c >> 4, col = (c & 15) * 8;
        int row = M0 + r;
        if (row < M) {
            short8 v = *(const short8*)(&As[r * 136 + col]);
            *(short8*)(Cb + (size_t)row * 512 + cb + col) = v;
        }
    }
}

// ---------------- GEMM2: x2[M,128] = h1[M,512] @ w2t[128,512]^T, N-split ----------
__global__ __launch_bounds__(256) void gemm2(const short* __restrict__ A,
                                             const short* __restrict__ Bt,
                                             short* __restrict__ C, int M) {
    __shared__ short As[32 * 72];     // reused as 32x72 C-staging
    __shared__ short Bs[64 * 72];
    int t = threadIdx.x;
    int w = t >> 6, L = t & 63, q = L >> 4, s = L & 15;
    int rw = (w >> 1) * 16, cw = (w & 1) * 32;
    int M0 = blockIdx.x * 32, N0 = blockIdx.y * 64;
    floatx4 acc[2] = {};
    for (int k0 = 0; k0 < 512; k0 += 64) {
        {   // A: 32 rows x 8 chunks of 8
            int r = t >> 3, col = (t & 7) * 8;
            int gr = M0 + r;
            short8 v = {};
            if (gr < M) v = *(const short8*)(A + (size_t)gr * 512 + k0 + col);
            *(short8*)(&As[r * 72 + col]) = v;
        }
        #pragma unroll
        for (int i = 0; i < 2; ++i) {   // B: 64 rows x 8 chunks
            int c = t + i * 256;
            int r = c >> 3, col = (c & 7) * 8;
            short8 v = *(const short8*)(Bt + (size_t)(N0 + r) * 512 + k0 + col);
            *(short8*)(&Bs[r * 72 + col]) = v;
        }
        __syncthreads();
        #pragma unroll
        for (int kk = 0; kk < 2; ++kk) {
            short8 a = *(const short8*)(&As[(rw + s) * 72 + kk * 32 + q * 8]);
            #pragma unroll
            for (int tt = 0; tt < 2; ++tt) {
                short8 b = *(const short8*)(&Bs[(cw + tt * 16 + s) * 72 + kk * 32 + q * 8]);
                acc[tt] = __builtin_amdgcn_mfma_f32_16x16x32_bf16(a, b, acc[tt], 0, 0, 0);
            }
        }
        __syncthreads();
    }
    #pragma unroll
    for (int tt = 0; tt < 2; ++tt) {
        #pragma unroll
        for (int rg = 0; rg < 4; ++rg) {
            int rl = rw + q * 4 + rg;
            As[rl * 72 + cw + tt * 16 + s] = f2b(acc[tt][rg]);
        }
    }
    __syncthreads();
    {   // 32 rows x 8 chunks of 8 = 256 chunks, one per thread
        int r = t >> 3, col = (t & 7) * 8;
        int row = M0 + r;
        if (row < M) {
            short8 v = *(const short8*)(&As[r * 72 + col]);
            *(short8*)(C + (size_t)row * 128 + N0 + col) = v;
        }
    }
}

// ---------------- Layer-1 GATv2: 1 wave/node, 8 ch/lane, 2-edge unroll ------------
__global__ void gat_l1(const short* __restrict__ xl, const short* __restrict__ xr,
                       const int* __restrict__ counts, const int* __restrict__ srcs,
                       const float* __restrict__ att, const float* __restrict__ bias,
                       short* __restrict__ h1, int Nn) {
    int i = (blockIdx.x * blockDim.x + threadIdx.x) >> 6;
    if (i >= Nn) return;
    int L = threadIdx.x & 63;
    int c0 = L * 8;
    float2v xrv[4], at[4];
    {
        int4v x4 = *(const int4v*)(xr + (size_t)i * 512 + c0);
        #pragma unroll
        for (int c = 0; c < 4; ++c) {
            xrv[c] = bpair(x4[c]);
            at[c].x = att[c0 + 2 * c];
            at[c].y = att[c0 + 2 * c + 1];
        }
    }
    float2v acc[4] = {};
    float dnm = 0.f;
    int k = i << 6;
    int deg = counts[i]; deg = deg > 64 ? 64 : deg;
    int ke = k + deg;
    for (; k + 1 < ke; k += 2) {
        int j0 = srcs[k], j1 = srcs[k + 1];
        int4v a4 = *(const int4v*)(xl + (size_t)j0 * 512 + c0);
        int4v b4 = *(const int4v*)(xl + (size_t)j1 * 512 + c0);
        float2v v0[4], v1[4];
        float2v p0 = {}, p1 = {};
        #pragma unroll
        for (int c = 0; c < 4; ++c) {
            v0[c] = bpair(a4[c]);
            float2v tv = v0[c] + xrv[c];
            p0 += at[c] * __builtin_elementwise_max(tv, 0.2f * tv);   // leaky 0.2
            v1[c] = bpair(b4[c]);
            float2v tw = v1[c] + xrv[c];
            p1 += at[c] * __builtin_elementwise_max(tw, 0.2f * tw);
        }
        float s0 = p0.x + p0.y, s1 = p1.x + p1.y;
        s0 += __shfl_xor(s0, 1, 64); s0 += __shfl_xor(s0, 2, 64); s0 += __shfl_xor(s0, 4, 64);
        s1 += __shfl_xor(s1, 1, 64); s1 += __shfl_xor(s1, 2, 64); s1 += __shfl_xor(s1, 4, 64);
        float e0 = __expf(s0), e1 = __expf(s1);
        dnm += e0 + e1;
        float2v e02; e02.x = e0; e02.y = e0;
        float2v e12; e12.x = e1; e12.y = e1;
        #pragma unroll
        for (int c = 0; c < 4; ++c) {
            acc[c] += e02 * v0[c];
            acc[c] += e12 * v1[c];
        }
    }
    if (k < ke) {
        int j = srcs[k];
        int4v a4 = *(const int4v*)(xl + (size_t)j * 512 + c0);
        float2v v0[4], p0 = {};
        #pragma unroll
        for (int c = 0; c < 4; ++c) {
            v0[c] = bpair(a4[c]);
            float2v tv = v0[c] + xrv[c];
            p0 += at[c] * __builtin_elementwise_max(tv, 0.2f * tv);
        }
        float s0 = p0.x + p0.y;
        s0 += __shfl_xor(s0, 1, 64); s0 += __shfl_xor(s0, 2, 64); s0 += __shfl_xor(s0, 4, 64);
        float e0 = __expf(s0);
        dnm += e0;
        float2v e02; e02.x = e0; e02.y = e0;
        #pragma unroll
        for (int c = 0; c < 4; ++c) acc[c] += e02 * v0[c];
    }
    float inv = 1.f / dnm;
    short8 o8;
    #pragma unroll
    for (int c = 0; c < 4; ++c) {
        float ox = fmaf(acc[c].x, inv, bias[c0 + 2 * c]);
        float oy = fmaf(acc[c].y, inv, bias[c0 + 2 * c + 1]);
        ox = ox > 0.f ? ox : __expf(ox) - 1.f;          // ELU
        oy = oy > 0.f ? oy : __expf(oy) - 1.f;
        o8[2 * c] = f2b(ox);
        o8[2 * c + 1] = f2b(oy);
    }
    *(short8*)(h1 + (size_t)i * 512 + c0) = o8;
}

// ---------------- Layer-2 GATv2 + final linear: 8-lane x 8-ch, 8 edges/iter -------
// One wave per node. Lane L: edge-slot g=L>>3, channels 8*(L&7)..+7.
__global__ __launch_bounds__(256) void gat_l2_fin(const short* __restrict__ x2,
                        const int* __restrict__ counts, const int* __restrict__ srcs,
                        const float* __restrict__ att, const float* __restrict__ bias,
                        const float* __restrict__ Wlin, const float* __restrict__ blin,
                        float* __restrict__ out, int Nn) {
    __shared__ float Ws[2048];
    __shared__ float bs[32];
    __shared__ float h2s[4][64];
    int t = threadIdx.x;
    for (int idx = t; idx < 2048; idx += 256) Ws[idx] = Wlin[idx];
    if (t < 32) bs[t] = blin[t];
    __syncthreads();
    int w = t >> 6, L = t & 63;
    int i = blockIdx.x * 4 + w;
    if (i >= Nn) return;
    int g = L >> 3;
    int c8 = (L & 7) * 8;
    float2v xrv[4], at[4];
    {
        int4v xv = *(const int4v*)(x2 + (size_t)i * 128 + 64 + c8);
        #pragma unroll
        for (int c = 0; c < 4; ++c) {
            xrv[c] = bpair(xv[c]);
            at[c].x = att[c8 + 2 * c];
            at[c].y = att[c8 + 2 * c + 1];
        }
    }
    float dnm = 0.f;
    float2v acc[4] = {};
    int kb = i << 6;
    int deg = counts[i]; deg = deg > 64 ? 64 : deg;
    int ke = kb + deg;
    for (int k0 = kb; k0 < ke; k0 += 8) {
        int k = k0 + g;
        bool val = k < ke;
        int j = srcs[val ? k : kb];         // slot kb always populated (deg >= 1)
        int4v vv = *(const int4v*)(x2 + (size_t)j * 128 + c8);
        float2v v[4], pp = {};
        #pragma unroll
        for (int c = 0; c < 4; ++c) {
            v[c] = bpair(vv[c]);
            float2v tv = v[c] + xrv[c];
            pp += at[c] * __builtin_elementwise_max(tv, 0.2f * tv);
        }
        float p = pp.x + pp.y;
        p += __shfl_xor(p, 1, 64); p += __shfl_xor(p, 2, 64); p += __shfl_xor(p, 4, 64);
        float e = val ? __expf(p) : 0.f;
        dnm += e;
        float2v e2; e2.x = e; e2.y = e;
        #pragma unroll
        for (int c = 0; c < 4; ++c) acc[c] += e2 * v[c];
    }
    // combine the 8 edge-groups (lanes sharing L&7 hold the same channels)
    #pragma unroll
    for (int m = 8; m <= 32; m <<= 1) {
        dnm += __shfl_xor(dnm, m, 64);
        #pragma unroll
        for (int c = 0; c < 4; ++c) {
            acc[c].x += __shfl_xor(acc[c].x, m, 64);
            acc[c].y += __shfl_xor(acc[c].y, m, 64);
        }
    }
    float inv = 1.f / dnm;
    float o[8];
    #pragma unroll
    for (int c = 0; c < 4; ++c) {
        o[2 * c]     = fmaf(acc[c].x, inv, bias[c8 + 2 * c]);
        o[2 * c + 1] = fmaf(acc[c].y, inv, bias[c8 + 2 * c + 1]);
    }
    #pragma unroll
    for (int c = 0; c < 8; ++c) o[c] = o[c] > 0.f ? o[c] : __expf(o[c]) - 1.f;  // ELU
    if (L < 8) {
        #pragma unroll
        for (int c = 0; c < 8; ++c) h2s[w][c8 + c] = o[c];   // wave-internal
    }
    int oc = L & 31;
    float accl = 0.f;
    #pragma unroll
    for (int kk = 0; kk < 16; ++kk) {
        floatx4 h = *(const floatx4*)(&h2s[w][kk * 4]);
        accl = fmaf(h[0], Ws[(kk * 4 + 0) * 32 + oc], accl);
        accl = fmaf(h[1], Ws[(kk * 4 + 1) * 32 + oc], accl);
        accl = fmaf(h[2], Ws[(kk * 4 + 2) * 32 + oc], accl);
        accl = fmaf(h[3], Ws[(kk * 4 + 3) * 32 + oc], accl);
    }
    if (L < 32) {
        float r = accl + bs[oc];
        r = r > 0.f ? r : __expf(r) - 1.f;
        out[(size_t)i * 32 + oc] = r;
    }
}

extern "C" void kernel_launch(void* const* d_in, const int* in_sizes, int n_in,
                              void* d_out, int out_size, void* d_ws, size_t ws_size,
                              hipStream_t stream) {
    const float* x    = (const float*)d_in[0];
    const int*   ei   = (const int*)d_in[1];
    const float* W1l  = (const float*)d_in[2];
    const float* W1r  = (const float*)d_in[3];
    const float* att1 = (const float*)d_in[4];
    const float* b1   = (const float*)d_in[5];
    const float* W2l  = (const float*)d_in[6];
    const float* W2r  = (const float*)d_in[7];
    const float* att2 = (const float*)d_in[8];
    const float* b2   = (const float*)d_in[9];
    const float* Wlin = (const float*)d_in[10];
    const float* blin = (const float*)d_in[11];

    const int N  = in_sizes[0] / 128;   // 20000
    const int E  = in_sizes[1] / 2;     // 320000
    const int ET = E + N;

    char* w = (char*)d_ws;
    size_t cur = 0;
    auto take = [&](size_t bytes) -> void* {
        void* p = w + cur;
        cur = (cur + bytes + 255) & ~(size_t)255;
        return p;
    };
    int*   counts = (int*)take((size_t)N * 4);
    int*   srcs   = (int*)take((size_t)N * 64 * 4);       // padded CSR, stride 64
    short* w1t    = (short*)take((size_t)1024 * 128 * 2);
    short* w2t    = (short*)take((size_t)128 * 512 * 2);
    short* xl1    = (short*)take((size_t)N * 512 * 2);
    short* xr1    = (short*)take((size_t)N * 512 * 2);
    short* h1     = (short*)take((size_t)N * 512 * 2);
    short* x2     = (short*)take((size_t)N * 128 * 2);    // xl2 | xr2

    hipMemsetAsync(counts, 0, (size_t)N * 4, stream);
    int nprep = ET > 196608 ? ET : 196608;
    prep_all<<<(nprep + 255) / 256, 256, 0, stream>>>(W1l, W1r, W2l, W2r, w1t, w2t,
                                                      ei, ei + E, E, N, counts, srcs);

    gemm1<<<dim3(8, (N + 63) / 64), 256, 0, stream>>>(x, w1t, xl1, xr1, N);
    gat_l1<<<(N + 3) / 4, 256, 0, stream>>>(xl1, xr1, counts, srcs, att1, b1, h1, N);

    gemm2<<<dim3((N + 31) / 32, 2), 256, 0, stream>>>(h1, w2t, x2, N);
    gat_l2_fin<<<(N + 3) / 4, 256, 0, stream>>>(x2, counts, srcs, att2, b2, Wlin, blin,
                                                (float*)d_out, N);
}

// Round 15
// 213.391 us; speedup vs baseline: 1.0523x; 1.0145x over previous
//
#include <hip/hip_runtime.h>
#include <hip/hip_bf16.h>

typedef __attribute__((ext_vector_type(8))) short short8;
typedef __attribute__((ext_vector_type(4))) short shortx4;
typedef __attribute__((ext_vector_type(4))) float floatx4;
typedef __attribute__((ext_vector_type(2))) float float2v;
typedef __attribute__((ext_vector_type(4))) int int4v;
typedef __attribute__((ext_vector_type(2))) int int2v;

__device__ __forceinline__ float b2f(short s) {
    unsigned u = ((unsigned)(unsigned short)s) << 16;
    float f; __builtin_memcpy(&f, &u, 4); return f;
}
__device__ __forceinline__ short f2b(float f) {
    __hip_bfloat16 hb = __float2bfloat16(f);   // RNE
    unsigned short us; __builtin_memcpy(&us, &hb, 2);
    return (short)us;
}
__device__ __forceinline__ float2v bpair(int p) {
    unsigned ulo = ((unsigned)p) << 16;
    unsigned uhi = ((unsigned)p) & 0xFFFF0000u;
    float flo, fhi;
    __builtin_memcpy(&flo, &ulo, 4);
    __builtin_memcpy(&fhi, &uhi, 4);
    float2v r; r.x = flo; r.y = fhi; return r;
}

// ---- prep: weight transposes + padded-CSR build (hist+scatter fused) ------------
__global__ void prep_all(const float* __restrict__ W1l, const float* __restrict__ W1r,
                         const float* __restrict__ W2l, const float* __restrict__ W2r,
                         short* __restrict__ w1t, short* __restrict__ w2t,
                         const int* __restrict__ esrc, const int* __restrict__ edst,
                         int E, int N, int* __restrict__ counts, int* __restrict__ srcs) {
    int tid = blockIdx.x * blockDim.x + threadIdx.x;
    int ET = E + N;
    if (tid < ET) {
        int d, s;
        if (tid < E) { d = edst[tid]; s = esrc[tid]; }
        else { d = tid - E; s = d; }
        int pos = atomicAdd(&counts[d], 1);
        if (pos < 64) srcs[(d << 6) + pos] = s;
    }
    int idx = tid;
    if (idx < 131072) {
        int n = idx >> 7, k = idx & 127;
        float v = (n < 512) ? W1l[k * 512 + n] : W1r[k * 512 + (n - 512)];
        w1t[idx] = f2b(v);
        return;
    }
    idx -= 131072;
    if (idx < 65536) {
        int n = idx >> 9, k = idx & 511;
        float v = (n < 64) ? W2l[k * 64 + n] : W2r[k * 64 + (n - 64)];
        w2t[idx] = f2b(v);
    }
}

// ---------------- GEMM1: x[M,128](f32) @ w1t[1024,128]^T -> xl1|xr1 [M,512] -------
// 64M x 2x128N serial tiles: A staged once (f32->bf16), Bs restaged per tile,
// Bs reused as C-stage for coalesced epilogue. grid (4, M/64).
__global__ __launch_bounds__(256) void gemm1(const float* __restrict__ X,
                                             const short* __restrict__ Bt,
                                             short* __restrict__ xl1, short* __restrict__ xr1,
                                             int M) {
    __shared__ short As[64 * 136];
    __shared__ short Bs[128 * 136];
    int t = threadIdx.x;
    int w = t >> 6, L = t & 63, q = L >> 4, s = L & 15;
    int M0 = blockIdx.y * 64, NB = blockIdx.x * 256;
    #pragma unroll
    for (int i = 0; i < 8; ++i) {       // A: 64 rows x 32 float4-chunks, cvt->bf16
        int c = t + i * 256;
        int r = c >> 5, col = (c & 31) * 4;
        int gr = M0 + r;
        floatx4 v = {};
        if (gr < M) v = *(const floatx4*)(X + (size_t)gr * 128 + col);
        shortx4 s4;
        #pragma unroll
        for (int j = 0; j < 4; ++j) s4[j] = f2b(v[j]);
        *(shortx4*)(&As[r * 136 + col]) = s4;
    }
    short8 a[4];
    #pragma unroll
    for (int tile = 0; tile < 2; ++tile) {
        int N0 = NB + tile * 128;
        if (tile) __syncthreads();      // prior write-phase Bs reads done
        #pragma unroll
        for (int i = 0; i < 8; ++i) {   // B: 128 rows x 16 chunks of 8 (bf16)
            int c = t + i * 256;
            int r = c >> 4, col = (c & 15) * 8;
            short8 v = *(const short8*)(Bt + (size_t)(N0 + r) * 128 + col);
            *(short8*)(&Bs[r * 136 + col]) = v;
        }
        __syncthreads();
        if (tile == 0) {
            #pragma unroll
            for (int kk = 0; kk < 4; ++kk)
                a[kk] = *(const short8*)(&As[(w * 16 + s) * 136 + kk * 32 + q * 8]);
        }
        floatx4 acc[8] = {};
        #pragma unroll
        for (int tt = 0; tt < 8; ++tt) {
            #pragma unroll
            for (int kk = 0; kk < 4; ++kk) {
                short8 b = *(const short8*)(&Bs[(tt * 16 + s) * 136 + kk * 32 + q * 8]);
                acc[tt] = __builtin_amdgcn_mfma_f32_16x16x32_bf16(a[kk], b, acc[tt], 0, 0, 0);
            }
        }
        __syncthreads();                // Bs MFMA reads done; reuse Bs as C stage
        #pragma unroll
        for (int tt = 0; tt < 8; ++tt) {
            #pragma unroll
            for (int rg = 0; rg < 4; ++rg) {
                int rl = w * 16 + q * 4 + rg;   // C/D: row=quad*4+reg, col=lane&15
                Bs[rl * 136 + tt * 16 + s] = f2b(acc[tt][rg]);
            }
        }
        __syncthreads();
        short* Cb = (N0 < 512) ? xl1 : xr1;
        int cb = (N0 < 512) ? N0 : N0 - 512;
        #pragma unroll
        for (int i = 0; i < 4; ++i) {   // 64 rows x 16 chunks of 8
            int c = t + i * 256;
            int r = c >> 4, col = (c & 15) * 8;
            int row = M0 + r;
            if (row < M) {
                short8 v = *(const short8*)(&Bs[r * 136 + col]);
                *(short8*)(Cb + (size_t)row * 512 + cb + col) = v;
            }
        }
    }
}

// ---------------- GEMM2: x2[M,128] = h1[M,512] @ w2t[128,512]^T, N-split ----------
__global__ __launch_bounds__(256) void gemm2(const short* __restrict__ A,
                                             const short* __restrict__ Bt,
                                             short* __restrict__ C, int M) {
    __shared__ short As[32 * 72];     // reused as 32x72 C-staging
    __shared__ short Bs[64 * 72];
    int t = threadIdx.x;
    int w = t >> 6, L = t & 63, q = L >> 4, s = L & 15;
    int rw = (w >> 1) * 16, cw = (w & 1) * 32;
    int M0 = blockIdx.x * 32, N0 = blockIdx.y * 64;
    floatx4 acc[2] = {};
    for (int k0 = 0; k0 < 512; k0 += 64) {
        {   // A: 32 rows x 8 chunks of 8
            int r = t >> 3, col = (t & 7) * 8;
            int gr = M0 + r;
            short8 v = {};
            if (gr < M) v = *(const short8*)(A + (size_t)gr * 512 + k0 + col);
            *(short8*)(&As[r * 72 + col]) = v;
        }
        #pragma unroll
        for (int i = 0; i < 2; ++i) {   // B: 64 rows x 8 chunks
            int c = t + i * 256;
            int r = c >> 3, col = (c & 7) * 8;
            short8 v = *(const short8*)(Bt + (size_t)(N0 + r) * 512 + k0 + col);
            *(short8*)(&Bs[r * 72 + col]) = v;
        }
        __syncthreads();
        #pragma unroll
        for (int kk = 0; kk < 2; ++kk) {
            short8 a = *(const short8*)(&As[(rw + s) * 72 + kk * 32 + q * 8]);
            #pragma unroll
            for (int tt = 0; tt < 2; ++tt) {
                short8 b = *(const short8*)(&Bs[(cw + tt * 16 + s) * 72 + kk * 32 + q * 8]);
                acc[tt] = __builtin_amdgcn_mfma_f32_16x16x32_bf16(a, b, acc[tt], 0, 0, 0);
            }
        }
        __syncthreads();
    }
    #pragma unroll
    for (int tt = 0; tt < 2; ++tt) {
        #pragma unroll
        for (int rg = 0; rg < 4; ++rg) {
            int rl = rw + q * 4 + rg;
            As[rl * 72 + cw + tt * 16 + s] = f2b(acc[tt][rg]);
        }
    }
    __syncthreads();
    {   // 32 rows x 8 chunks of 8 = 256 chunks, one per thread
        int r = t >> 3, col = (t & 7) * 8;
        int row = M0 + r;
        if (row < M) {
            short8 v = *(const short8*)(&As[r * 72 + col]);
            *(short8*)(C + (size_t)row * 128 + N0 + col) = v;
        }
    }
}

// ---------------- Layer-1 GATv2: 1 wave/node, 8 ch/lane, 2-edge unroll ------------
__global__ void gat_l1(const short* __restrict__ xl, const short* __restrict__ xr,
                       const int* __restrict__ counts, const int* __restrict__ srcs,
                       const float* __restrict__ att, const float* __restrict__ bias,
                       short* __restrict__ h1, int Nn) {
    int i = (blockIdx.x * blockDim.x + threadIdx.x) >> 6;
    if (i >= Nn) return;
    int L = threadIdx.x & 63;
    int c0 = L * 8;
    float2v xrv[4], at[4];
    {
        int4v x4 = *(const int4v*)(xr + (size_t)i * 512 + c0);
        #pragma unroll
        for (int c = 0; c < 4; ++c) {
            xrv[c] = bpair(x4[c]);
            at[c].x = att[c0 + 2 * c];
            at[c].y = att[c0 + 2 * c + 1];
        }
    }
    float2v acc[4] = {};
    float dnm = 0.f;
    int k = i << 6;
    int deg = counts[i]; deg = deg > 64 ? 64 : deg;
    int ke = k + deg;
    for (; k + 1 < ke; k += 2) {
        int j0 = srcs[k], j1 = srcs[k + 1];
        int4v a4 = *(const int4v*)(xl + (size_t)j0 * 512 + c0);
        int4v b4 = *(const int4v*)(xl + (size_t)j1 * 512 + c0);
        float2v v0[4], v1[4];
        float2v p0 = {}, p1 = {};
        #pragma unroll
        for (int c = 0; c < 4; ++c) {
            v0[c] = bpair(a4[c]);
            float2v tv = v0[c] + xrv[c];
            p0 += at[c] * __builtin_elementwise_max(tv, 0.2f * tv);   // leaky 0.2
            v1[c] = bpair(b4[c]);
            float2v tw = v1[c] + xrv[c];
            p1 += at[c] * __builtin_elementwise_max(tw, 0.2f * tw);
        }
        float s0 = p0.x + p0.y, s1 = p1.x + p1.y;
        s0 += __shfl_xor(s0, 1, 64); s0 += __shfl_xor(s0, 2, 64); s0 += __shfl_xor(s0, 4, 64);
        s1 += __shfl_xor(s1, 1, 64); s1 += __shfl_xor(s1, 2, 64); s1 += __shfl_xor(s1, 4, 64);
        float e0 = __expf(s0), e1 = __expf(s1);
        dnm += e0 + e1;
        float2v e02; e02.x = e0; e02.y = e0;
        float2v e12; e12.x = e1; e12.y = e1;
        #pragma unroll
        for (int c = 0; c < 4; ++c) {
            acc[c] += e02 * v0[c];
            acc[c] += e12 * v1[c];
        }
    }
    if (k < ke) {
        int j = srcs[k];
        int4v a4 = *(const int4v*)(xl + (size_t)j * 512 + c0);
        float2v v0[4], p0 = {};
        #pragma unroll
        for (int c = 0; c < 4; ++c) {
            v0[c] = bpair(a4[c]);
            float2v tv = v0[c] + xrv[c];
            p0 += at[c] * __builtin_elementwise_max(tv, 0.2f * tv);
        }
        float s0 = p0.x + p0.y;
        s0 += __shfl_xor(s0, 1, 64); s0 += __shfl_xor(s0, 2, 64); s0 += __shfl_xor(s0, 4, 64);
        float e0 = __expf(s0);
        dnm += e0;
        float2v e02; e02.x = e0; e02.y = e0;
        #pragma unroll
        for (int c = 0; c < 4; ++c) acc[c] += e02 * v0[c];
    }
    float inv = 1.f / dnm;
    short8 o8;
    #pragma unroll
    for (int c = 0; c < 4; ++c) {
        float ox = fmaf(acc[c].x, inv, bias[c0 + 2 * c]);
        float oy = fmaf(acc[c].y, inv, bias[c0 + 2 * c + 1]);
        ox = ox > 0.f ? ox : __expf(ox) - 1.f;          // ELU
        oy = oy > 0.f ? oy : __expf(oy) - 1.f;
        o8[2 * c] = f2b(ox);
        o8[2 * c + 1] = f2b(oy);
    }
    *(short8*)(h1 + (size_t)i * 512 + c0) = o8;
}

// ---------------- Layer-2 GATv2 + final linear: 16-lane x 4-ch, 4 edges/iter ------
__global__ __launch_bounds__(256) void gat_l2_fin(const short* __restrict__ x2,
                        const int* __restrict__ counts, const int* __restrict__ srcs,
                        const float* __restrict__ att, const float* __restrict__ bias,
                        const float* __restrict__ Wlin, const float* __restrict__ blin,
                        float* __restrict__ out, int Nn) {
    __shared__ float Ws[2048];
    __shared__ float bs[32];
    __shared__ float h2s[4][64];
    int t = threadIdx.x;
    for (int idx = t; idx < 2048; idx += 256) Ws[idx] = Wlin[idx];
    if (t < 32) bs[t] = blin[t];
    __syncthreads();
    int w = t >> 6, L = t & 63;
    int i = blockIdx.x * 4 + w;
    if (i >= Nn) return;
    int g = L >> 4;
    int c4 = (L & 15) * 4;
    float2v xrv[2], at[2];
    {
        int2v xv = *(const int2v*)(x2 + (size_t)i * 128 + 64 + c4);
        xrv[0] = bpair(xv.x);
        xrv[1] = bpair(xv.y);
        floatx4 a4 = *(const floatx4*)(att + c4);
        at[0].x = a4[0]; at[0].y = a4[1];
        at[1].x = a4[2]; at[1].y = a4[3];
    }
    float dnm = 0.f;
    float2v acc0 = {}, acc1 = {};
    int kb = i << 6;
    int deg = counts[i]; deg = deg > 64 ? 64 : deg;
    int ke = kb + deg;
    for (int k0 = kb; k0 < ke; k0 += 4) {
        int k = k0 + g;
        bool val = k < ke;
        int j = srcs[val ? k : kb];         // slot kb always populated (deg >= 1)
        int2v vv = *(const int2v*)(x2 + (size_t)j * 128 + c4);
        float2v v0 = bpair(vv.x), v1 = bpair(vv.y);
        float2v t0 = v0 + xrv[0], t1 = v1 + xrv[1];
        float2v pp = at[0] * __builtin_elementwise_max(t0, 0.2f * t0)
                   + at[1] * __builtin_elementwise_max(t1, 0.2f * t1);
        float p = pp.x + pp.y;
        p += __shfl_xor(p, 1, 64); p += __shfl_xor(p, 2, 64);
        p += __shfl_xor(p, 4, 64); p += __shfl_xor(p, 8, 64);   // 16-lane reduce
        float e = val ? __expf(p) : 0.f;
        dnm += e;
        float2v e2; e2.x = e; e2.y = e;
        acc0 += e2 * v0;
        acc1 += e2 * v1;
    }
    #pragma unroll
    for (int m = 16; m <= 32; m <<= 1) {
        dnm += __shfl_xor(dnm, m, 64);
        acc0.x += __shfl_xor(acc0.x, m, 64);
        acc0.y += __shfl_xor(acc0.y, m, 64);
        acc1.x += __shfl_xor(acc1.x, m, 64);
        acc1.y += __shfl_xor(acc1.y, m, 64);
    }
    float inv = 1.f / dnm;
    floatx4 bv = *(const floatx4*)(bias + c4);
    float o0 = fmaf(acc0.x, inv, bv[0]);
    float o1 = fmaf(acc0.y, inv, bv[1]);
    float o2 = fmaf(acc1.x, inv, bv[2]);
    float o3 = fmaf(acc1.y, inv, bv[3]);
    o0 = o0 > 0.f ? o0 : __expf(o0) - 1.f;   // ELU (h2)
    o1 = o1 > 0.f ? o1 : __expf(o1) - 1.f;
    o2 = o2 > 0.f ? o2 : __expf(o2) - 1.f;
    o3 = o3 > 0.f ? o3 : __expf(o3) - 1.f;
    if (L < 16) {
        floatx4 hv; hv[0] = o0; hv[1] = o1; hv[2] = o2; hv[3] = o3;
        *(floatx4*)(&h2s[w][c4]) = hv;       // wave-internal: no barrier needed
    }
    int oc = L & 31;
    float accl = 0.f;
    #pragma unroll
    for (int kk = 0; kk < 16; ++kk) {
        floatx4 h = *(const floatx4*)(&h2s[w][kk * 4]);
        accl = fmaf(h[0], Ws[(kk * 4 + 0) * 32 + oc], accl);
        accl = fmaf(h[1], Ws[(kk * 4 + 1) * 32 + oc], accl);
        accl = fmaf(h[2], Ws[(kk * 4 + 2) * 32 + oc], accl);
        accl = fmaf(h[3], Ws[(kk * 4 + 3) * 32 + oc], accl);
    }
    if (L < 32) {
        float r = accl + bs[oc];
        r = r > 0.f ? r : __expf(r) - 1.f;
        out[(size_t)i * 32 + oc] = r;
    }
}

extern "C" void kernel_launch(void* const* d_in, const int* in_sizes, int n_in,
                              void* d_out, int out_size, void* d_ws, size_t ws_size,
                              hipStream_t stream) {
    const float* x    = (const float*)d_in[0];
    const int*   ei   = (const int*)d_in[1];
    const float* W1l  = (const float*)d_in[2];
    const float* W1r  = (const float*)d_in[3];
    const float* att1 = (const float*)d_in[4];
    const float* b1   = (const float*)d_in[5];
    const float* W2l  = (const float*)d_in[6];
    const float* W2r  = (const float*)d_in[7];
    const float* att2 = (const float*)d_in[8];
    const float* b2   = (const float*)d_in[9];
    const float* Wlin = (const float*)d_in[10];
    const float* blin = (const float*)d_in[11];

    const int N  = in_sizes[0] / 128;   // 20000
    const int E  = in_sizes[1] / 2;     // 320000
    const int ET = E + N;

    char* w = (char*)d_ws;
    size_t cur = 0;
    auto take = [&](size_t bytes) -> void* {
        void* p = w + cur;
        cur = (cur + bytes + 255) & ~(size_t)255;
        return p;
    };
    int*   counts = (int*)take((size_t)N * 4);
    int*   srcs   = (int*)take((size_t)N * 64 * 4);       // padded CSR, stride 64
    short* w1t    = (short*)take((size_t)1024 * 128 * 2);
    short* w2t    = (short*)take((size_t)128 * 512 * 2);
    short* xl1    = (short*)take((size_t)N * 512 * 2);
    short* xr1    = (short*)take((size_t)N * 512 * 2);
    short* h1     = (short*)take((size_t)N * 512 * 2);
    short* x2     = (short*)take((size_t)N * 128 * 2);    // xl2 | xr2

    hipMemsetAsync(counts, 0, (size_t)N * 4, stream);
    int nprep = ET > 196608 ? ET : 196608;
    prep_all<<<(nprep + 255) / 256, 256, 0, stream>>>(W1l, W1r, W2l, W2r, w1t, w2t,
                                                      ei, ei + E, E, N, counts, srcs);

    gemm1<<<dim3(4, (N + 63) / 64), 256, 0, stream>>>(x, w1t, xl1, xr1, N);
    gat_l1<<<(N + 3) / 4, 256, 0, stream>>>(xl1, xr1, counts, srcs, att1, b1, h1, N);

    gemm2<<<dim3((N + 31) / 32, 2), 256, 0, stream>>>(h1, w2t, x2, N);
    gat_l2_fin<<<(N + 3) / 4, 256, 0, stream>>>(x2, counts, srcs, att2, b2, Wlin, blin,
                                                (float*)d_out, N);
}